// Round 6
// baseline (122.939 us; speedup 1.0000x reference)
//
#include <hip/hip_runtime.h>
#include <hip/hip_cooperative_groups.h>
#include <math.h>

namespace cg = cooperative_groups;

#define BB 64
#define LL 512
#define DD 768
#define HH 768
#define KK 128
#define NBLK 192
#define NTHR 512

static __device__ __forceinline__ float4 fmax4(float4 a, float4 b) {
    float4 r;
    r.x = fmaxf(a.x, b.x); r.y = fmaxf(a.y, b.y);
    r.z = fmaxf(a.z, b.z); r.w = fmaxf(a.w, b.w);
    return r;
}

// ---------------------------------------------------------------------------
// One cooperative kernel, three phases separated by grid.sync():
//  A: (64 b x 3 parts) ballot-scan (prefetched) + span-max gather -> feat(ws)
//  B: (12 j-tiles x 16 b-tiles of 4, k in halves) h = relu(feat@W1+b1) (ws)
//  C: (blocks 0..63, k in quarters) out = h@W2 + b2
// ---------------------------------------------------------------------------
__global__ __launch_bounds__(NTHR, 2) void halton_coop_kernel(
    const float* __restrict__ enc,        // (B, L, D)
    const float* __restrict__ W1,         // (D, H)
    const float* __restrict__ b1,         // (H)
    const float* __restrict__ W2,         // (H, K)
    const float* __restrict__ b2,         // (K)
    const int*   __restrict__ valid_mask, // (B, L)
    const int*   __restrict__ pos_span,   // (B, 2)
    float*       __restrict__ feat,       // ws (B, D)
    float*       __restrict__ h,          // ws (B, H)
    float*       __restrict__ out)        // (B, K)
{
    cg::grid_group grid = cg::this_grid();

    __shared__ int    s_idx[40];
    __shared__ int    s_count;
    __shared__ float4 s_redA[8][64];      // 8 KB
    __shared__ float  s_feat[4 * DD];     // 12 KB
    __shared__ float  s_partB[4][64];     // 1 KB
    __shared__ float  s_h[HH];            // 3 KB
    __shared__ float  s_partC[4][KK];     // 2 KB

    const int blk  = blockIdx.x;
    const int tid  = threadIdx.x;
    const int lane = tid & 63;

    // ======== Phase A: compaction scan + span-max gather ====================
    {
        const int b    = blk & 63;
        const int part = blk >> 6;        // 0..2

        if (tid < 64) {                   // wave 0: prefetched ballot scan
            int v[8];
            #pragma unroll
            for (int c = 0; c < 8; ++c)   // 8 independent loads -> 1 latency
                v[c] = valid_mask[b * LL + c * 64 + tid];
            int count = 0;
            #pragma unroll
            for (int c = 0; c < 8; ++c) {
                unsigned long long mk = __ballot(v[c] == 1);
                if (v[c] == 1) {
                    int rank = count + __popcll(mk & ((1ull << tid) - 1ull));
                    if (rank < 40) s_idx[rank] = c * 64 + tid;
                }
                count += __popcll(mk);
            }
            if (tid == 0) s_count = count;
        }
        __syncthreads();

        const int count = s_count;
        const int lo    = pos_span[b * 2 + 0];
        const int hi    = pos_span[b * 2 + 1];   // <= 39 by construction
        const int pend  = min(hi, count - 1);
        const int g     = tid >> 6;              // row-group 0..7
        const int fcol  = part * 64 + lane;      // float4 col in 192-wide row

        float4 m = make_float4(-INFINITY, -INFINITY, -INFINITY, -INFINITY);
        for (int p = lo + g; p <= pend; p += 8) {
            m = fmax4(m, ((const float4*)&enc[((long)b * LL + s_idx[p]) * DD])[fcol]);
        }
        if (hi >= count) m = fmax4(m, make_float4(0.f, 0.f, 0.f, 0.f));
        s_redA[g][lane] = m;
        __syncthreads();

        if (g == 0) {
            float4 r = s_redA[0][lane];
            #pragma unroll
            for (int q = 1; q < 8; ++q) r = fmax4(r, s_redA[q][lane]);
            ((float4*)&feat[(long)b * DD])[fcol] = r;
        }
    }

    __threadfence();
    grid.sync();

    // ======== Phase B: h = relu(feat @ W1 + b1) =============================
    {
        const int jt    = blk / 16;       // 0..11
        const int bt    = blk - jt * 16;  // 0..15
        const int jbase = jt * 64;
        const int bbase = bt * 4;

        for (int i = tid; i < 4 * DD / 4; i += NTHR)
            ((float4*)s_feat)[i] = ((const float4*)&feat[(long)bbase * DD])[i];
        __syncthreads();

        const int j   = jbase + lane;
        const int sub = tid >> 6;         // 0..7
        const int bl  = sub & 3;          // batch within tile
        const int kh  = sub >> 2;         // k-half 0..1
        const float4* f4 = (const float4*)&s_feat[bl * DD];
        const float*  wp = &W1[j];

        float a0 = (kh == 0) ? b1[j] : 0.f, a1 = 0.f, a2 = 0.f, a3 = 0.f;
        #pragma unroll 4
        for (int i = 0; i < 96; ++i) {
            const int k4 = kh * 96 + i;
            const float4 fv = f4[k4];                 // LDS b128 broadcast
            const float* wk = &wp[(long)k4 * 4 * HH];
            a0 += fv.x * wk[0 * HH];                  // coalesced
            a1 += fv.y * wk[1 * HH];
            a2 += fv.z * wk[2 * HH];
            a3 += fv.w * wk[3 * HH];
        }
        const float part_ = (a0 + a1) + (a2 + a3);
        if (kh == 1) s_partB[bl][lane] = part_;
        __syncthreads();
        if (kh == 0)
            h[(long)(bbase + bl) * HH + j] = fmaxf(part_ + s_partB[bl][lane], 0.f);
    }

    __threadfence();
    grid.sync();

    // ======== Phase C: out = h @ W2 + b2 (blocks 0..63) =====================
    if (blk < BB) {
        const int b = blk;
        if (tid < HH / 4)
            ((float4*)s_h)[tid] = ((const float4*)&h[(long)b * HH])[tid];
        __syncthreads();

        const int col = tid & 127;
        const int kq  = tid >> 7;         // k-quarter 0..3
        const float4* h4 = (const float4*)&s_h[kq * (HH / 4)];
        const float*  wp = &W2[(long)(kq * (HH / 4)) * KK + col];

        float a0 = 0.f, a1 = 0.f, a2 = 0.f, a3 = 0.f;
        #pragma unroll 8
        for (int i = 0; i < HH / 16; ++i) {           // 48 iters
            const float4 hv = h4[i];                  // LDS b128 broadcast
            const float* wj = &wp[(long)i * 4 * KK];
            a0 += hv.x * wj[0 * KK];                  // coalesced
            a1 += hv.y * wj[1 * KK];
            a2 += hv.z * wj[2 * KK];
            a3 += hv.w * wj[3 * KK];
        }
        s_partC[kq][col] = (a0 + a1) + (a2 + a3);
        __syncthreads();
        if (tid < KK)
            out[b * KK + tid] = ((s_partC[0][tid] + s_partC[1][tid]) +
                                 (s_partC[2][tid] + s_partC[3][tid])) + b2[tid];
    }
}

extern "C" void kernel_launch(void* const* d_in, const int* in_sizes, int n_in,
                              void* d_out, int out_size, void* d_ws, size_t ws_size,
                              hipStream_t stream) {
    const float* enc        = (const float*)d_in[0];
    const float* W1         = (const float*)d_in[1];
    const float* b1         = (const float*)d_in[2];
    const float* W2         = (const float*)d_in[3];
    const float* b2         = (const float*)d_in[4];
    const int*   valid_mask = (const int*)d_in[5];
    const int*   pos_span   = (const int*)d_in[6];
    // d_in[7] = mask_span: dead code (mask_feat unused by the reference output)
    float* out  = (float*)d_out;
    float* feat = (float*)d_ws;
    float* h    = (float*)d_ws + BB * DD;

    void* args[] = {
        (void*)&enc, (void*)&W1, (void*)&b1, (void*)&W2, (void*)&b2,
        (void*)&valid_mask, (void*)&pos_span, (void*)&feat, (void*)&h, (void*)&out
    };
    hipLaunchCooperativeKernel((const void*)halton_coop_kernel,
                               dim3(NBLK), dim3(NTHR), args, 0, stream);
}

// Round 7
// 30.760 us; speedup vs baseline: 3.9967x; 3.9967x over previous
//
#include <hip/hip_runtime.h>
#include <math.h>

#define BB 64
#define LL 512
#define DD 768
#define HH 768
#define KK 128
#define NTHR 768

static __device__ __forceinline__ float4 fmax4(float4 a, float4 b) {
    float4 r;
    r.x = fmaxf(a.x, b.x); r.y = fmaxf(a.y, b.y);
    r.z = fmaxf(a.z, b.z); r.w = fmaxf(a.w, b.w);
    return r;
}

// ---------------------------------------------------------------------------
// Fully-fused, one block per batch, no grid sync (per-batch chain is private):
//   A: ballot-scan compaction + span-max gather -> s_feat (LDS)
//   B: s_h = relu(s_feat @ W1 + b1)              (W1 read once per block)
//   C: out[b] = s_h @ W2 + b2                    (k split 6 ways, LDS combine)
// grid: 64 blocks ; block: 768 threads (12 waves).
// ---------------------------------------------------------------------------
__global__ __launch_bounds__(NTHR, 1) void halton_fused1_kernel(
    const float* __restrict__ enc,        // (B, L, D)
    const float* __restrict__ W1,         // (D, H)
    const float* __restrict__ b1,         // (H)
    const float* __restrict__ W2,         // (H, K)
    const float* __restrict__ b2,         // (K)
    const int*   __restrict__ valid_mask, // (B, L)
    const int*   __restrict__ pos_span,   // (B, 2)
    float*       __restrict__ out)        // (B, K)
{
    __shared__ int    s_idx[40];
    __shared__ int    s_count;
    __shared__ float4 s_redA[4][DD / 4];  // 12 KB
    __shared__ float  s_feat[DD];         // 3 KB
    __shared__ float  s_h[HH];            // 3 KB
    __shared__ float  s_partC[6][KK];     // 3 KB

    const int b    = blockIdx.x;
    const int tid  = threadIdx.x;
    const int lane = tid & 63;
    const int w    = tid >> 6;            // wave 0..11

    // ======== Phase A: compaction scan + span-max gather ====================
    if (tid < 64) {                       // wave 0: prefetched ballot scan
        int v[8];
        #pragma unroll
        for (int c = 0; c < 8; ++c)       // 8 independent loads, one latency
            v[c] = valid_mask[b * LL + c * 64 + tid];
        int count = 0;
        #pragma unroll
        for (int c = 0; c < 8; ++c) {
            unsigned long long mk = __ballot(v[c] == 1);
            if (v[c] == 1) {
                int rank = count + __popcll(mk & ((1ull << tid) - 1ull));
                if (rank < 40) s_idx[rank] = c * 64 + tid;
            }
            count += __popcll(mk);
        }
        if (tid == 0) s_count = count;
    }
    __syncthreads();

    {
        const int count = s_count;
        const int lo    = pos_span[b * 2 + 0];
        const int hi    = pos_span[b * 2 + 1];   // <= 39 by construction
        const int pend  = min(hi, count - 1);

        const int part = w % 3;           // 0..2 (64-col chunk of 192 f4 cols)
        const int g    = w / 3;           // row-group 0..3
        const int fcol = part * 64 + lane;

        // two accumulators -> load pairs in flight; <=5 dependent pairs
        float4 m0 = make_float4(-INFINITY, -INFINITY, -INFINITY, -INFINITY);
        float4 m1 = m0;
        for (int p = lo + g; p <= pend; p += 8) {
            m0 = fmax4(m0, ((const float4*)&enc[((long)b * LL + s_idx[p]) * DD])[fcol]);
            if (p + 4 <= pend)
                m1 = fmax4(m1, ((const float4*)&enc[((long)b * LL + s_idx[p + 4]) * DD])[fcol]);
        }
        m0 = fmax4(m0, m1);
        if (hi >= count)                  // zero row(s) inside span
            m0 = fmax4(m0, make_float4(0.f, 0.f, 0.f, 0.f));
        s_redA[g][fcol] = m0;
    }
    __syncthreads();

    if (w < 3) {                          // 192 threads: fmax tree over groups
        const int fcol = w * 64 + lane;
        float4 r = fmax4(fmax4(s_redA[0][fcol], s_redA[1][fcol]),
                         fmax4(s_redA[2][fcol], s_redA[3][fcol]));
        ((float4*)s_feat)[fcol] = r;
    }
    __syncthreads();

    // ======== Phase B: s_h = relu(s_feat @ W1 + b1) =========================
    {
        const int j = tid;                // 0..767
        const float4* f4 = (const float4*)s_feat;
        const float*  wp = &W1[j];

        float a0 = b1[j], a1 = 0.f, a2 = 0.f, a3 = 0.f;
        #pragma unroll 4
        for (int k4 = 0; k4 < DD / 4; ++k4) {
            const float4 fv = f4[k4];                 // LDS b128 broadcast
            const float* wk = &wp[(long)k4 * 4 * HH];
            a0 += fv.x * wk[0 * HH];                  // coalesced, W1 read once
            a1 += fv.y * wk[1 * HH];
            a2 += fv.z * wk[2 * HH];
            a3 += fv.w * wk[3 * HH];
        }
        s_h[j] = fmaxf((a0 + a1) + (a2 + a3), 0.f);
    }
    __syncthreads();

    // ======== Phase C: out[b] = s_h @ W2 + b2 ===============================
    {
        const int col = tid & 127;
        const int seg = tid >> 7;         // k-sixth 0..5 (uniform per wave)
        const float4* h4 = (const float4*)&s_h[seg * (HH / 6)];
        const float*  wp = &W2[(long)(seg * (HH / 6)) * KK + col];

        float a0 = 0.f, a1 = 0.f, a2 = 0.f, a3 = 0.f;
        #pragma unroll 8
        for (int i = 0; i < HH / 24; ++i) {           // 32 iters
            const float4 hv = h4[i];                  // LDS b128 broadcast
            const float* wj = &wp[(long)i * 4 * KK];
            a0 += hv.x * wj[0 * KK];                  // coalesced
            a1 += hv.y * wj[1 * KK];
            a2 += hv.z * wj[2 * KK];
            a3 += hv.w * wj[3 * KK];
        }
        s_partC[seg][col] = (a0 + a1) + (a2 + a3);
    }
    __syncthreads();

    if (tid < KK) {
        out[b * KK + tid] = ((s_partC[0][tid] + s_partC[1][tid]) +
                             (s_partC[2][tid] + s_partC[3][tid]) +
                             (s_partC[4][tid] + s_partC[5][tid])) + b2[tid];
    }
}

extern "C" void kernel_launch(void* const* d_in, const int* in_sizes, int n_in,
                              void* d_out, int out_size, void* d_ws, size_t ws_size,
                              hipStream_t stream) {
    const float* enc        = (const float*)d_in[0];
    const float* W1         = (const float*)d_in[1];
    const float* b1         = (const float*)d_in[2];
    const float* W2         = (const float*)d_in[3];
    const float* b2         = (const float*)d_in[4];
    const int*   valid_mask = (const int*)d_in[5];
    const int*   pos_span   = (const int*)d_in[6];
    // d_in[7] = mask_span: dead code (mask_feat unused by the reference output)
    float* out = (float*)d_out;

    halton_fused1_kernel<<<BB, NTHR, 0, stream>>>(enc, W1, b1, W2, b2,
                                                  valid_mask, pos_span, out);
}

// Round 8
// 25.050 us; speedup vs baseline: 4.9078x; 1.2280x over previous
//
#include <hip/hip_runtime.h>
#include <math.h>

#define BB 64
#define LL 512
#define DD 768
#define HH 768
#define KK 128

static __device__ __forceinline__ float4 fmax4(float4 a, float4 b) {
    float4 r;
    r.x = fmaxf(a.x, b.x); r.y = fmaxf(a.y, b.y);
    r.z = fmaxf(a.z, b.z); r.w = fmaxf(a.w, b.w);
    return r;
}

// ws layout (floats): feat[64*768] | h[64*768]
#define FEAT_OFF 0
#define H_OFF    (BB * DD)

// ---------------------------------------------------------------------------
// Kernel A: compaction scan + span-max gather (R5 structure).
// grid: (B, 3 parts) = 192 blocks ; block: 512 (8 waves).
// ---------------------------------------------------------------------------
__global__ __launch_bounds__(512) void halton_feat_kernel(
    const float* __restrict__ enc,        // (B, L, D)
    const int*   __restrict__ valid_mask, // (B, L)
    const int*   __restrict__ pos_span,   // (B, 2)
    float*       __restrict__ feat)       // (B, D)
{
    __shared__ int    s_idx[40];
    __shared__ int    s_count;
    __shared__ float4 s_red[8][64];       // 8 KB

    const int b    = blockIdx.x;
    const int part = blockIdx.y;          // 0..2
    const int tid  = threadIdx.x;

    if (tid < 64) {                       // wave 0: prefetched ballot scan
        int v[8];
        #pragma unroll
        for (int c = 0; c < 8; ++c)       // 8 independent loads, one latency
            v[c] = valid_mask[b * LL + c * 64 + tid];
        int count = 0;
        #pragma unroll
        for (int c = 0; c < 8; ++c) {
            unsigned long long mk = __ballot(v[c] == 1);
            if (v[c] == 1) {
                int rank = count + __popcll(mk & ((1ull << tid) - 1ull));
                if (rank < 40) s_idx[rank] = c * 64 + tid;
            }
            count += __popcll(mk);
        }
        if (tid == 0) s_count = count;
    }
    __syncthreads();

    const int count = s_count;
    const int lo    = pos_span[b * 2 + 0];
    const int hi    = pos_span[b * 2 + 1];   // <= 39 by construction
    const int pend  = min(hi, count - 1);

    const int c4   = tid & 63;            // float4 column within this part
    const int g    = tid >> 6;            // row-group 0..7
    const int fcol = part * 64 + c4;

    float4 m = make_float4(-INFINITY, -INFINITY, -INFINITY, -INFINITY);
    for (int p = lo + g; p <= pend; p += 8) {
        m = fmax4(m, ((const float4*)&enc[((long)b * LL + s_idx[p]) * DD])[fcol]);
    }
    if (hi >= count) m = fmax4(m, make_float4(0.f, 0.f, 0.f, 0.f));
    s_red[g][c4] = m;
    __syncthreads();

    if (g == 0) {
        float4 r = s_red[0][c4];
        #pragma unroll
        for (int q = 1; q < 8; ++q) r = fmax4(r, s_red[q][c4]);
        ((float4*)&feat[(long)b * DD])[fcol] = r;
    }
}

// ---------------------------------------------------------------------------
// Kernel B: h = relu(feat @ W1 + b1), W1 read ONCE per block.
// grid: (12 j-tiles of 64, 8 b-tiles of 8) = 96 blocks ; block: 512 (8 waves).
// wave w = k-slice [96w, 96w+96) ; thread = 1 column ; 8 batch accumulators.
// Each W1 element is loaded once and FMA'd against 8 batches.
// ---------------------------------------------------------------------------
__global__ __launch_bounds__(512) void halton_gemm1_kernel(
    const float* __restrict__ feat,  // (B, D)
    const float* __restrict__ W1,    // (D, H)
    const float* __restrict__ b1,    // (H)
    float*       __restrict__ h)     // (B, H)
{
    __shared__ float s_feat[8 * DD];     // 24 KB
    __shared__ float s_part[8][8][64];   // [kslice][batch][col] 16 KB

    const int tid   = threadIdx.x;
    const int jbase = blockIdx.x * 64;
    const int bbase = blockIdx.y * 8;
    const int col   = tid & 63;
    const int w     = tid >> 6;          // k-slice 0..7

    {
        const float4* src = (const float4*)&feat[bbase * DD];
        float4*       dst = (float4*)s_feat;
        for (int i = tid; i < 8 * DD / 4; i += 512) dst[i] = src[i];
    }
    __syncthreads();

    const int j = jbase + col;
    float acc[8] = {0.f, 0.f, 0.f, 0.f, 0.f, 0.f, 0.f, 0.f};

    // k4 walks 24 float4-groups of this wave's 96-k slice
    #pragma unroll 2
    for (int k4 = 0; k4 < 24; ++k4) {
        const int k = w * 96 + k4 * 4;
        // 4 W1 rows, each loaded once per block (coalesced 256B/wave)
        const float w0 = W1[(k + 0) * HH + j];
        const float w1 = W1[(k + 1) * HH + j];
        const float w2 = W1[(k + 2) * HH + j];
        const float w3 = W1[(k + 3) * HH + j];
        #pragma unroll
        for (int bb = 0; bb < 8; ++bb) {
            const float4 fv = *(const float4*)&s_feat[bb * DD + k]; // broadcast
            acc[bb] += fv.x * w0 + fv.y * w1 + fv.z * w2 + fv.w * w3;
        }
    }
    #pragma unroll
    for (int bb = 0; bb < 8; ++bb) s_part[w][bb][col] = acc[bb];
    __syncthreads();

    // combine: thread -> (batch = tid>>6, col), sum 8 k-slices
    {
        const int bl = tid >> 6;
        float r = b1[jbase + col];
        #pragma unroll
        for (int q = 0; q < 8; ++q) r += s_part[q][bl][col];
        h[(long)(bbase + bl) * HH + jbase + col] = fmaxf(r, 0.f);
    }
}

// ---------------------------------------------------------------------------
// Kernel C: out = h @ W2 + b2, W2 read ONCE per block.
// grid: (2 col-tiles of 64, 64 batches) = 128 blocks ; block: 384 (6 waves).
// wave = k-slice of 128 ; thread = 1 column ; LDS combine.
// ---------------------------------------------------------------------------
__global__ __launch_bounds__(384) void halton_gemm2_kernel(
    const float* __restrict__ h,     // (B, H)
    const float* __restrict__ W2,    // (H, K)
    const float* __restrict__ b2,    // (K)
    float*       __restrict__ out)   // (B, K)
{
    __shared__ float s_h[HH];        // 3 KB
    __shared__ float s_part[6][64];  // 1.5 KB

    const int tid = threadIdx.x;
    const int b   = blockIdx.y;
    const int col = blockIdx.x * 64 + (tid & 63);
    const int seg = tid >> 6;        // k-slice 0..5

    if (tid < HH / 4)
        ((float4*)s_h)[tid] = ((const float4*)&h[(long)b * HH])[tid];
    __syncthreads();

    float a0 = 0.f, a1 = 0.f, a2 = 0.f, a3 = 0.f;
    #pragma unroll 4
    for (int i4 = 0; i4 < 32; ++i4) {
        const int k = seg * 128 + i4 * 4;
        const float4 hv = *(const float4*)&s_h[k];   // LDS b128 broadcast
        a0 += hv.x * W2[(k + 0) * KK + col];         // coalesced, once/block
        a1 += hv.y * W2[(k + 1) * KK + col];
        a2 += hv.z * W2[(k + 2) * KK + col];
        a3 += hv.w * W2[(k + 3) * KK + col];
    }
    s_part[seg][tid & 63] = (a0 + a1) + (a2 + a3);
    __syncthreads();

    if (tid < 64) {
        float r = b2[col];
        #pragma unroll
        for (int q = 0; q < 6; ++q) r += s_part[q][tid];
        out[b * KK + col] = r;
    }
}

extern "C" void kernel_launch(void* const* d_in, const int* in_sizes, int n_in,
                              void* d_out, int out_size, void* d_ws, size_t ws_size,
                              hipStream_t stream) {
    const float* enc        = (const float*)d_in[0];
    const float* W1         = (const float*)d_in[1];
    const float* b1         = (const float*)d_in[2];
    const float* W2         = (const float*)d_in[3];
    const float* b2         = (const float*)d_in[4];
    const int*   valid_mask = (const int*)d_in[5];
    const int*   pos_span   = (const int*)d_in[6];
    // d_in[7] = mask_span: dead code (mask_feat unused by the reference output)
    float* out  = (float*)d_out;
    float* feat = (float*)d_ws + FEAT_OFF;
    float* h    = (float*)d_ws + H_OFF;

    halton_feat_kernel<<<dim3(BB, 3), 512, 0, stream>>>(enc, valid_mask, pos_span, feat);
    halton_gemm1_kernel<<<dim3(12, 8), 512, 0, stream>>>(feat, W1, b1, h);
    halton_gemm2_kernel<<<dim3(2, BB), 384, 0, stream>>>(h, W2, b2, out);
}

// Round 9
// 20.084 us; speedup vs baseline: 6.1212x; 1.2472x over previous
//
#include <hip/hip_runtime.h>
#include <math.h>

#define BB 64
#define LL 512
#define DD 768
#define HH 768
#define KK 128

static __device__ __forceinline__ float4 fmax4(float4 a, float4 b) {
    float4 r;
    r.x = fmaxf(a.x, b.x); r.y = fmaxf(a.y, b.y);
    r.z = fmaxf(a.z, b.z); r.w = fmaxf(a.w, b.w);
    return r;
}

// ws layout (floats): feat[64*768] | h[64*768]
#define FEAT_OFF 0
#define H_OFF    (BB * DD)

// ---------------------------------------------------------------------------
// Kernel A: compaction scan + span-max gather.
// grid: (B, 3 parts) = 192 blocks ; block: 512 (8 waves).
// ---------------------------------------------------------------------------
__global__ __launch_bounds__(512) void halton_feat_kernel(
    const float* __restrict__ enc,        // (B, L, D)
    const int*   __restrict__ valid_mask, // (B, L)
    const int*   __restrict__ pos_span,   // (B, 2)
    float*       __restrict__ feat)       // (B, D)
{
    __shared__ int    s_idx[40];
    __shared__ int    s_count;
    __shared__ float4 s_red[8][64];       // 8 KB

    const int b    = blockIdx.x;
    const int part = blockIdx.y;          // 0..2
    const int tid  = threadIdx.x;

    // hoist span loads off the post-sync critical path
    const int lo = pos_span[b * 2 + 0];
    const int hi = pos_span[b * 2 + 1];   // <= 39 by construction

    if (tid < 64) {                       // wave 0: prefetched ballot scan
        int v[8];
        #pragma unroll
        for (int c = 0; c < 8; ++c)       // 8 independent loads, one latency
            v[c] = valid_mask[b * LL + c * 64 + tid];
        int count = 0;
        #pragma unroll
        for (int c = 0; c < 8; ++c) {
            unsigned long long mk = __ballot(v[c] == 1);
            if (v[c] == 1) {
                int rank = count + __popcll(mk & ((1ull << tid) - 1ull));
                if (rank < 40) s_idx[rank] = c * 64 + tid;
            }
            count += __popcll(mk);
        }
        if (tid == 0) s_count = count;
    }
    __syncthreads();

    const int count = s_count;
    const int pend  = min(hi, count - 1);

    const int c4   = tid & 63;            // float4 column within this part
    const int g    = tid >> 6;            // row-group 0..7
    const int fcol = part * 64 + c4;

    float4 m = make_float4(-INFINITY, -INFINITY, -INFINITY, -INFINITY);
    for (int p = lo + g; p <= pend; p += 8) {
        m = fmax4(m, ((const float4*)&enc[((long)b * LL + s_idx[p]) * DD])[fcol]);
    }
    if (hi >= count) m = fmax4(m, make_float4(0.f, 0.f, 0.f, 0.f));
    s_red[g][c4] = m;
    __syncthreads();

    if (g == 0) {
        float4 r = s_red[0][c4];
        #pragma unroll
        for (int q = 1; q < 8; ++q) r = fmax4(r, s_red[q][c4]);
        ((float4*)&feat[(long)b * DD])[fcol] = r;
    }
}

// ---------------------------------------------------------------------------
// Kernel B: h = relu(feat @ W1 + b1).
// grid: (6 j-tiles of 128, 32 b-tiles of 2) = 192 blocks ; block: 512 (8 waves)
// wave w = k-slice [96w, 96w+96) ; thread = 2 cols (j, j+64) x 2 batches.
// Per k4: 2 LDS broadcasts (vs 8 in R8), 8 W1 loads, 32 FMAs -> VALU/L2-bound.
// ---------------------------------------------------------------------------
__global__ __launch_bounds__(512) void halton_gemm1_kernel(
    const float* __restrict__ feat,  // (B, D)
    const float* __restrict__ W1,    // (D, H)
    const float* __restrict__ b1,    // (H)
    float*       __restrict__ h)     // (B, H)
{
    __shared__ float s_feat[2 * DD];       // 6 KB
    __shared__ float s_part[8][2][128];    // [kslice][batch][col] 8 KB

    const int tid   = threadIdx.x;
    const int jbase = blockIdx.x * 128;
    const int bbase = blockIdx.y * 2;
    const int lane  = tid & 63;
    const int w     = tid >> 6;            // k-slice 0..7

    {
        const float4* src = (const float4*)&feat[bbase * DD];
        float4*       dst = (float4*)s_feat;
        for (int i = tid; i < 2 * DD / 4; i += 512) dst[i] = src[i];
    }
    __syncthreads();

    const int j0 = jbase + lane;
    const int j1 = j0 + 64;
    const float4* f40 = (const float4*)&s_feat[0];
    const float4* f41 = (const float4*)&s_feat[DD];

    float a00 = 0.f, a01 = 0.f, a10 = 0.f, a11 = 0.f;
    #pragma unroll 4
    for (int k4 = 0; k4 < 24; ++k4) {
        const int kf = w * 24 + k4;        // float4 index into feat row
        const int k  = kf * 4;
        const float4 fv0 = f40[kf];        // LDS b128 broadcast (batch 0)
        const float4 fv1 = f41[kf];        // LDS b128 broadcast (batch 1)
        const float w00 = W1[(k + 0) * HH + j0];
        const float w01 = W1[(k + 0) * HH + j1];
        const float w10 = W1[(k + 1) * HH + j0];
        const float w11 = W1[(k + 1) * HH + j1];
        const float w20 = W1[(k + 2) * HH + j0];
        const float w21 = W1[(k + 2) * HH + j1];
        const float w30 = W1[(k + 3) * HH + j0];
        const float w31 = W1[(k + 3) * HH + j1];
        a00 += fv0.x * w00 + fv0.y * w10 + fv0.z * w20 + fv0.w * w30;
        a01 += fv0.x * w01 + fv0.y * w11 + fv0.z * w21 + fv0.w * w31;
        a10 += fv1.x * w00 + fv1.y * w10 + fv1.z * w20 + fv1.w * w30;
        a11 += fv1.x * w01 + fv1.y * w11 + fv1.z * w21 + fv1.w * w31;
    }
    s_part[w][0][lane]      = a00;
    s_part[w][0][lane + 64] = a01;
    s_part[w][1][lane]      = a10;
    s_part[w][1][lane + 64] = a11;
    __syncthreads();

    // combine: threads 0..255 -> (batch = t>>7, col = t&127), sum 8 k-slices
    if (tid < 256) {
        const int bl  = tid >> 7;
        const int col = tid & 127;
        float r = b1[jbase + col];
        #pragma unroll
        for (int q = 0; q < 8; ++q) r += s_part[q][bl][col];
        h[(long)(bbase + bl) * HH + jbase + col] = fmaxf(r, 0.f);
    }
}

// ---------------------------------------------------------------------------
// Kernel C: out = h @ W2 + b2, W2 read once per block.
// grid: (2 col-tiles of 64, 64 batches) = 128 blocks ; block: 384 (6 waves).
// ---------------------------------------------------------------------------
__global__ __launch_bounds__(384) void halton_gemm2_kernel(
    const float* __restrict__ h,     // (B, H)
    const float* __restrict__ W2,    // (H, K)
    const float* __restrict__ b2,    // (K)
    float*       __restrict__ out)   // (B, K)
{
    __shared__ float s_h[HH];        // 3 KB
    __shared__ float s_part[6][64];  // 1.5 KB

    const int tid = threadIdx.x;
    const int b   = blockIdx.y;
    const int col = blockIdx.x * 64 + (tid & 63);
    const int seg = tid >> 6;        // k-slice 0..5

    if (tid < HH / 4)
        ((float4*)s_h)[tid] = ((const float4*)&h[(long)b * HH])[tid];
    __syncthreads();

    float a0 = 0.f, a1 = 0.f, a2 = 0.f, a3 = 0.f;
    #pragma unroll 4
    for (int i4 = 0; i4 < 32; ++i4) {
        const int k = seg * 128 + i4 * 4;
        const float4 hv = *(const float4*)&s_h[k];   // LDS b128 broadcast
        a0 += hv.x * W2[(k + 0) * KK + col];         // coalesced, once/block
        a1 += hv.y * W2[(k + 1) * KK + col];
        a2 += hv.z * W2[(k + 2) * KK + col];
        a3 += hv.w * W2[(k + 3) * KK + col];
    }
    s_part[seg][tid & 63] = (a0 + a1) + (a2 + a3);
    __syncthreads();

    if (tid < 64) {
        float r = b2[col];
        #pragma unroll
        for (int q = 0; q < 6; ++q) r += s_part[q][tid];
        out[b * KK + col] = r;
    }
}

extern "C" void kernel_launch(void* const* d_in, const int* in_sizes, int n_in,
                              void* d_out, int out_size, void* d_ws, size_t ws_size,
                              hipStream_t stream) {
    const float* enc        = (const float*)d_in[0];
    const float* W1         = (const float*)d_in[1];
    const float* b1         = (const float*)d_in[2];
    const float* W2         = (const float*)d_in[3];
    const float* b2         = (const float*)d_in[4];
    const int*   valid_mask = (const int*)d_in[5];
    const int*   pos_span   = (const int*)d_in[6];
    // d_in[7] = mask_span: dead code (mask_feat unused by the reference output)
    float* out  = (float*)d_out;
    float* feat = (float*)d_ws + FEAT_OFF;
    float* h    = (float*)d_ws + H_OFF;

    halton_feat_kernel<<<dim3(BB, 3), 512, 0, stream>>>(enc, valid_mask, pos_span, feat);
    halton_gemm1_kernel<<<dim3(6, 32), 512, 0, stream>>>(feat, W1, b1, h);
    halton_gemm2_kernel<<<dim3(2, BB), 384, 0, stream>>>(h, W2, b2, out);
}